// Round 17
// baseline (519.906 us; speedup 1.0000x reference)
//
#include <hip/hip_runtime.h>
#include <hip/hip_fp16.h>
#include <type_traits>

#define N_NODES 50000
#define NROW    50176                    // padded rows per graph (multiple of 1024)
#define N_EDGES 800000
#define BATCH   4
#define DIM     64
#define NEG_SLOPE 0.2f
#define K_CHUNK 16
#define CHUNK_E (N_EDGES / K_CHUNK)      // 50000 exactly
#define NTOT2   (BATCH * NROW)           // 200704 = 196*1024 exactly
#define SCAN_BLOCKS (NTOT2 / 1024)       // 196
#define HALF_ROWS 25088                  // NROW/2
#define HALF_WORDS 12544                 // HALF_ROWS/2 packed u16 words
#define GBLK    ((N_NODES + 63) / 64)    // 782 gemm blocks per graph
#define AGG_BLKS (NROW / 4)              // 12544

struct HPtr4 { const __half* p[4]; };

// ---------------------------------------------------------------------------
// Index dtype detector (int64 vs int32).
// ---------------------------------------------------------------------------
__global__ void detect_idx_kernel(const unsigned* __restrict__ ei, int* flag) {
    __shared__ int any;
    if (threadIdx.x == 0) any = 0;
    __syncthreads();
    unsigned v = ei[threadIdx.x * 2 + 1];
    if (v != 0) atomicOr(&any, 1);
    __syncthreads();
    if (threadIdx.x == 0) *flag = (any ? 0 : 1);
}

__device__ __forceinline__ int load_idx(const void* p, long long i, int is64) {
    if (is64) return (int)(((const long long*)p)[i]);
    return ((const int*)p)[i];
}

// ---------------------------------------------------------------------------
// Histogram stage 1: private LDS histogram per (graph, chunk, row-half).
// ---------------------------------------------------------------------------
__global__ __launch_bounds__(256)
void hist_partial_kernel(const void* __restrict__ ei, const int* __restrict__ flag,
                         unsigned* __restrict__ P32) {
    __shared__ unsigned lds[HALF_WORDS];          // 50 KB
    int t = threadIdx.x;
    int b = blockIdx.x >> 5;
    int k = (blockIdx.x >> 1) & (K_CHUNK - 1);
    int h = blockIdx.x & 1;
    for (int i = t; i < HALF_WORDS; i += 256) lds[i] = 0;
    __syncthreads();
    const int is64 = *flag;
    const int rowLo = h * HALF_ROWS;
    const long long base = (long long)b * 2LL * N_EDGES + (long long)k * CHUNK_E;
    for (int i = t; i < CHUNK_E; i += 256) {
        int row = load_idx(ei, base + i, is64);
        unsigned r = (unsigned)(row - rowLo);
        if (r < HALF_ROWS)
            atomicAdd(&lds[r >> 1], 1u << ((r & 1) * 16));
    }
    __syncthreads();
    unsigned* dst = P32 + (long long)(b * K_CHUNK + k) * (NROW / 2) + h * HALF_WORDS;
    for (int i = t; i < HALF_WORDS; i += 256) dst[i] = lds[i];
}

// ---------------------------------------------------------------------------
// Stage 2: per (b,row): deg = sum_k counts; P16 -> exclusive chunk prefix.
// ---------------------------------------------------------------------------
__global__ __launch_bounds__(256)
void merge_prefix_kernel(unsigned short* __restrict__ P16, int* __restrict__ deg4) {
    int gid = blockIdx.x * 256 + threadIdx.x;
    if (gid >= NTOT2) return;
    int b = gid / NROW;
    int row = gid - b * NROW;
    unsigned short* p = P16 + (long long)(b * K_CHUNK) * NROW + row;
    int run = 0;
#pragma unroll
    for (int k = 0; k < K_CHUNK; ++k) {
        int c = p[(long long)k * NROW];
        p[(long long)k * NROW] = (unsigned short)run;
        run += c;
    }
    deg4[gid] = run;
}

// ---------------------------------------------------------------------------
// Hierarchical exclusive scan over deg4[NTOT2] -> rowptr4.
// ---------------------------------------------------------------------------
__global__ __launch_bounds__(256)
void scan_partial_kernel(const int* __restrict__ deg, int* __restrict__ bsum) {
    __shared__ int sdata[256];
    int t = threadIdx.x;
    int base = blockIdx.x * 1024;
    int s = 0;
#pragma unroll
    for (int i = 0; i < 4; ++i) s += deg[base + i * 256 + t];
    sdata[t] = s;
    __syncthreads();
    for (int off = 128; off > 0; off >>= 1) {
        if (t < off) sdata[t] += sdata[t + off];
        __syncthreads();
    }
    if (t == 0) bsum[blockIdx.x] = sdata[0];
}

__global__ __launch_bounds__(256)
void scan_bsum_kernel(int* __restrict__ bsum, int* __restrict__ rowptr) {
    __shared__ int sdata[256];
    int t = threadIdx.x;
    int v = (t < SCAN_BLOCKS) ? bsum[t] : 0;
    sdata[t] = v;
    __syncthreads();
    for (int off = 1; off < 256; off <<= 1) {
        int x = (t >= off) ? sdata[t - off] : 0;
        __syncthreads();
        sdata[t] += x;
        __syncthreads();
    }
    if (t < SCAN_BLOCKS) bsum[t] = sdata[t] - v;
    if (t == 255) rowptr[NTOT2] = sdata[255];
}

__global__ __launch_bounds__(256)
void scan_apply_kernel(const int* __restrict__ deg, const int* __restrict__ bsum,
                       int* __restrict__ rowptr) {
    __shared__ int sdata[256];
    int t = threadIdx.x;
    int base = blockIdx.x * 1024 + t * 4;
    int4 q = *(const int4*)(deg + base);          // NTOT2 exact multiple of 1024
    int s = q.x + q.y + q.z + q.w;
    sdata[t] = s;
    __syncthreads();
    for (int off = 1; off < 256; off <<= 1) {
        int x = (t >= off) ? sdata[t - off] : 0;
        __syncthreads();
        sdata[t] += x;
        __syncthreads();
    }
    int run = bsum[blockIdx.x] + sdata[t] - s;
    rowptr[base + 0] = run; run += q.x;
    rowptr[base + 1] = run; run += q.y;
    rowptr[base + 2] = run; run += q.z;
    rowptr[base + 3] = run;
}

// ---------------------------------------------------------------------------
// Deterministic placement (R11 proven form): NO global atomics.
// colw entry u32 = col(u16) | fp16 weight << 16
// ---------------------------------------------------------------------------
__global__ __launch_bounds__(512)
void placement_kernel(const void* __restrict__ ei, const float* __restrict__ ew,
                      const int* __restrict__ flag,
                      const unsigned short* __restrict__ P16,
                      const int* __restrict__ rowptr4,
                      unsigned* __restrict__ colw, int bStart, int sub) {
    __shared__ unsigned lds[HALF_WORDS];          // 50 KB packed u16 cursors
    const int is64 = *flag;
    const int nc = gridDim.x >> 4;                // classes = nGraphs*2
    int c = blockIdx.x % nc;
    int k = blockIdx.x / nc;                      // chunk 0..15
    int b = bStart + (c >> 1);
    int h = c & 1;
    const int rowLo = h * HALF_ROWS;
    const unsigned* psrc =
        (const unsigned*)(P16 + (long long)(b * K_CHUNK + k) * NROW + rowLo);
    for (int i = threadIdx.x; i < HALF_WORDS; i += 512) lds[i] = psrc[i];
    __syncthreads();
    const long long ebase = (long long)b * 2LL * N_EDGES + (long long)k * CHUNK_E;
    const float* ewb = ew + (long long)b * N_EDGES + (long long)k * CHUNK_E;
    const int* rp = rowptr4 + b * NROW;
    for (int i = threadIdx.x; i < CHUNK_E; i += 512) {
        int row = load_idx(ei, ebase + i, is64);
        unsigned r = (unsigned)(row - rowLo);
        if (r < HALF_ROWS) {
            int col = load_idx(ei, ebase + N_EDGES + i, is64);
            __half hw = __float2half_rn(ewb[i]);
            unsigned short wb = *(unsigned short*)&hw;
            unsigned old = atomicAdd(&lds[r >> 1], 1u << ((r & 1) * 16));
            int my = (int)((old >> ((r & 1) * 16)) & 0xffffu);
            int pos = rp[row] + my - sub;
            colw[pos] = (unsigned)col | ((unsigned)wb << 16);
        }
    }
}

// ---------------------------------------------------------------------------
// S = act(X) @ W -> fp16 [N][64]. TIN = float (bx) or __half (fp16 h1).
// ---------------------------------------------------------------------------
template <bool LEAKY, typename TIN>
__device__ __forceinline__
void gemm_body(const TIN* __restrict__ X, const float* __restrict__ Wl,
               __half* __restrict__ S, int blk, int t) {
    int dq = t & 15;
    int rl = t >> 4;
    int rowBase = blk * 64;
    for (int r = rl; r < 64; r += 16) {
        int row = rowBase + r;
        if (row >= N_NODES) break;
        const TIN* xr = X + (long long)row * DIM;
        float4 acc = {0.f, 0.f, 0.f, 0.f};
        if constexpr (std::is_same<TIN, float>::value) {
#pragma unroll
            for (int k = 0; k < 64; k += 4) {
                float4 xv = *(const float4*)(xr + k);
                if (LEAKY) {
                    xv.x = xv.x > 0.f ? xv.x : NEG_SLOPE * xv.x;
                    xv.y = xv.y > 0.f ? xv.y : NEG_SLOPE * xv.y;
                    xv.z = xv.z > 0.f ? xv.z : NEG_SLOPE * xv.z;
                    xv.w = xv.w > 0.f ? xv.w : NEG_SLOPE * xv.w;
                }
#pragma unroll
                for (int kk = 0; kk < 4; ++kk) {
                    float xs = kk == 0 ? xv.x : kk == 1 ? xv.y : kk == 2 ? xv.z : xv.w;
                    float4 wv = *(const float4*)(&Wl[(k + kk) * 64 + dq * 4]);
                    acc.x += xs * wv.x;
                    acc.y += xs * wv.y;
                    acc.z += xs * wv.z;
                    acc.w += xs * wv.w;
                }
            }
        } else {
#pragma unroll
            for (int k = 0; k < 64; k += 8) {
                float4 raw = *(const float4*)((const char*)xr + k * 2);  // 8 halfs
                const __half2* hp = (const __half2*)&raw;
                float xs[8];
#pragma unroll
                for (int j = 0; j < 4; ++j) {
                    float2 f = __half22float2(hp[j]);
                    xs[2 * j]     = f.x;
                    xs[2 * j + 1] = f.y;
                }
                if (LEAKY) {
#pragma unroll
                    for (int j = 0; j < 8; ++j)
                        xs[j] = xs[j] > 0.f ? xs[j] : NEG_SLOPE * xs[j];
                }
#pragma unroll
                for (int j = 0; j < 8; ++j) {
                    float4 wv = *(const float4*)(&Wl[(k + j) * 64 + dq * 4]);
                    acc.x += xs[j] * wv.x;
                    acc.y += xs[j] * wv.y;
                    acc.z += xs[j] * wv.z;
                    acc.w += xs[j] * wv.w;
                }
            }
        }
        __half2* o = (__half2*)(S + (long long)row * DIM + dq * 4);
        o[0] = __floats2half2_rn(acc.x, acc.y);
        o[1] = __floats2half2_rn(acc.z, acc.w);
    }
}

template <bool LEAKY, typename TIN>
__global__ __launch_bounds__(256)
void gemm_kernel(const TIN* __restrict__ X, const float* __restrict__ W,
                 __half* __restrict__ S) {
    __shared__ float Wl[64 * 64];
    int t = threadIdx.x;
    for (int i = t; i < 64 * 64; i += 256) Wl[i] = W[i];
    __syncthreads();
    gemm_body<LEAKY, TIN>(X, Wl, S, blockIdx.x, t);
}

// ---------------------------------------------------------------------------
// FUSED L1 aggregate + bias + leaky + @W1: after the slot-combine every lane
// of the wave holds the full h1 row (lane l: dims 2l,2l+1). Apply b0+leaky,
// then compute s1 = leaky(h1) @ W1 in-register: W1 in LDS, k-split across
// slots (slot0: k<32, slot1: k>=32), 16 iters of shfl-broadcast + FMA, final
// shfl_xor(32) combine. h1 NEVER touches memory; gemm2 pass eliminated.
// Grid: 2 graphs per dispatch (bStart, bStart+1); dst0/dst1 = s1 regions.
// ---------------------------------------------------------------------------
__global__ __launch_bounds__(256)
void agg1_fused_kernel(const int* __restrict__ rowptr4, const unsigned* __restrict__ colw,
                       const __half* __restrict__ src, const float* __restrict__ bias,
                       const float* __restrict__ W1,
                       __half* __restrict__ dst0, __half* __restrict__ dst1,
                       int bStart) {
    __shared__ float Wl[64 * 64];
    for (int i = threadIdx.x; i < 64 * 64; i += 256) Wl[i] = W1[i];
    __syncthreads();

    int bi = blockIdx.x / AGG_BLKS;                // 0 or 1
    int node = (blockIdx.x % AGG_BLKS) * 4 + (threadIdx.x >> 6);
    int tl = threadIdx.x & 63;
    int lane = tl & 31;                            // dim pair (2l, 2l+1)
    int slot = tl >> 5;
    int b = bStart + bi;
    if (node >= N_NODES) return;
    const int* rp = rowptr4 + b * NROW;
    int s = rp[node];
    int e = rp[node + 1];
    float2 acc = {0.f, 0.f};
    for (int k0 = s + slot; k0 < e; k0 += 16) {
        unsigned c[8];
        float2 v[8];
        bool m[8];
#pragma unroll
        for (int j = 0; j < 8; ++j) {
            int ki = k0 + 2 * j;
            m[j] = ki < e;
            c[j] = m[j] ? colw[ki] : 0u;
        }
#pragma unroll
        for (int j = 0; j < 8; ++j) {
            if (m[j]) {
                __half2 h = *(const __half2*)(src + (long long)(c[j] & 0xffffu) * DIM
                                              + 2 * lane);
                v[j] = __half22float2(h);
            } else {
                v[j] = make_float2(0.f, 0.f);
            }
        }
#pragma unroll
        for (int j = 0; j < 8; ++j) {
            unsigned short wb = (unsigned short)(c[j] >> 16);
            float w = __half2float(*(__half*)&wb);
            acc.x += w * v[j].x;
            acc.y += w * v[j].y;
        }
    }
    acc.x += __shfl_xor(acc.x, 32, 64);
    acc.y += __shfl_xor(acc.y, 32, 64);

    // h1 row complete in-register: bias + leaky
    float2 bb = *(const float2*)(bias + 2 * lane);
    float hx = acc.x + bb.x; hx = hx > 0.f ? hx : NEG_SLOPE * hx;
    float hy = acc.y + bb.y; hy = hy > 0.f ? hy : NEG_SLOPE * hy;

    // mini-GEMM: o[2l,2l+1] = sum_k h1[k] * W1[k][2l,2l+1]; k-split by slot
    float2 o = {0.f, 0.f};
    const int kbase = slot * 32;
#pragma unroll
    for (int i = 0; i < 16; ++i) {
        int kl = kbase + 2 * i;
        int srcLane = (kbase >> 1) + i;            // lane holding dims (kl, kl+1)
        float h0 = __shfl(hx, srcLane, 64);
        float h1v = __shfl(hy, srcLane, 64);
        float2 w0 = *(const float2*)(&Wl[kl * 64 + 2 * lane]);
        float2 w1 = *(const float2*)(&Wl[(kl + 1) * 64 + 2 * lane]);
        o.x += h0 * w0.x + h1v * w1.x;
        o.y += h0 * w0.y + h1v * w1.y;
    }
    o.x += __shfl_xor(o.x, 32, 64);
    o.y += __shfl_xor(o.y, 32, 64);
    if (slot == 0) {
        __half* dst = bi == 0 ? dst0 : dst1;
        __half2* hp = (__half2*)dst + (long long)node * (DIM / 2) + lane;
        *hp = __floats2half2_rn(o.x, o.y);
    }
}

// ---------------------------------------------------------------------------
// Pull aggregation (final layer / fallback), predicated window loop.
// HOUT=true: fp16 h1 into out slice (small path); HOUT=false: final f32.
// ---------------------------------------------------------------------------
template <bool HOUT>
__global__ __launch_bounds__(256)
void aggregate_kernel(const int* __restrict__ rowptr4, const unsigned* __restrict__ colw,
                      HPtr4 srcs, const float* __restrict__ bias,
                      void* __restrict__ dstBase, int bStart, int colwLocal) {
    int bi = blockIdx.x / AGG_BLKS;
    int node = (blockIdx.x % AGG_BLKS) * 4 + (threadIdx.x >> 6);
    int tl = threadIdx.x & 63;
    int lane = tl & 31;
    int slot = tl >> 5;
    int b = bStart + bi;
    if (node >= N_NODES) return;
    const __half* __restrict__ src = srcs.p[b];
    const int* rp = rowptr4 + b * NROW;
    int sub = colwLocal ? b * N_EDGES : 0;
    int s = rp[node] - sub;
    int e = rp[node + 1] - sub;
    float2 acc = {0.f, 0.f};
    for (int k0 = s + slot; k0 < e; k0 += 16) {
        unsigned c[8];
        float2 v[8];
        bool m[8];
#pragma unroll
        for (int j = 0; j < 8; ++j) {
            int ki = k0 + 2 * j;
            m[j] = ki < e;
            c[j] = m[j] ? colw[ki] : 0u;
        }
#pragma unroll
        for (int j = 0; j < 8; ++j) {
            if (m[j]) {
                __half2 h = *(const __half2*)(src + (long long)(c[j] & 0xffffu) * DIM
                                              + 2 * lane);
                v[j] = __half22float2(h);
            } else {
                v[j] = make_float2(0.f, 0.f);
            }
        }
#pragma unroll
        for (int j = 0; j < 8; ++j) {
            unsigned short wb = (unsigned short)(c[j] >> 16);
            float w = __half2float(*(__half*)&wb);
            acc.x += w * v[j].x;
            acc.y += w * v[j].y;
        }
    }
    acc.x += __shfl_xor(acc.x, 32, 64);
    acc.y += __shfl_xor(acc.y, 32, 64);
    if (slot == 0) {
        float2 bb = *(const float2*)(bias + 2 * lane);
        float ox = acc.x + bb.x;
        float oy = acc.y + bb.y;
        char* gp = (char*)dstBase + (long long)b * ((long long)N_NODES * DIM * 4);
        if constexpr (HOUT) {
            __half2* hp = (__half2*)gp + (long long)node * (DIM / 2) + lane;
            *hp = __floats2half2_rn(ox, oy);
        } else {
            float2* fp = (float2*)gp + (long long)node * (DIM / 2) + lane;
            *fp = make_float2(ox, oy);
        }
    }
}

extern "C" void kernel_launch(void* const* d_in, const int* in_sizes, int n_in,
                              void* d_out, int out_size, void* d_ws, size_t ws_size,
                              hipStream_t stream) {
    const float* bx = (const float*)d_in[0];
    const void*  ei = d_in[1];
    const float* ew = (const float*)d_in[2];
    const float* W0 = (const float*)d_in[3];
    const float* b0 = (const float*)d_in[4];
    const float* W1 = (const float*)d_in[5];
    const float* b1 = (const float*)d_in[6];
    float* out = (float*)d_out;

    // ---- workspace layout (big path = 40,029,696 B, proven R5-R16) ----
    char* ws = (char*)d_ws;
    int*      flag     = (int*)ws;                       // [0,256)
    int*      bsum     = (int*)(ws + 256);               // [256,1280)
    int*      deg4     = (int*)(ws + 1280);              // [1280,804096)
    int*      rowptr4  = (int*)(ws + 804096);            // [804096,1607168)
    unsigned* P32      = (unsigned*)(ws + 1607168);      // 6.42 MB
    unsigned short* P16 = (unsigned short*)P32;
    __half*   support0 = (__half*)(ws + 8029696);        // 6.4 MB
    unsigned* colw     = (unsigned*)(ws + 14429696);     // 12.8 MB packed
    const size_t NEED_BIG = 40029696ull;
    const bool big = ws_size >= NEED_BIG;
    const long long ND = (long long)N_NODES * DIM;

    detect_idx_kernel<<<1, 64, 0, stream>>>((const unsigned*)ei, flag);

    // ---- batched atomic-free CSR skeleton ----
    hist_partial_kernel<<<BATCH * K_CHUNK * 2, 256, 0, stream>>>(ei, flag, P32);
    merge_prefix_kernel<<<(NTOT2 + 255) / 256, 256, 0, stream>>>(P16, deg4);
    scan_partial_kernel<<<SCAN_BLOCKS, 256, 0, stream>>>(deg4, bsum);
    scan_bsum_kernel<<<1, 256, 0, stream>>>(bsum, rowptr4);
    scan_apply_kernel<<<SCAN_BLOCKS, 256, 0, stream>>>(deg4, bsum, rowptr4);

    // ---- layer-1 support (graph-independent, fp16) ----
    gemm_kernel<false, float><<<GBLK, 256, 0, stream>>>(bx, W0, support0);

    if (big) {
        placement_kernel<<<BATCH * K_CHUNK * 2, 512, 0, stream>>>(
            ei, ew, flag, P16, rowptr4, colw, 0, 0);

        // s1 regions (6.4 MB each): dead-P16 region + free tail, reused per pair
        __half* s1a = (__half*)(ws + 1607168);      // P16 dead after placement
        __half* s1b = (__half*)(ws + 27229696);     // tail after colw
        HPtr4 s1 = {{s1a, s1b, s1a, s1b}};

        // pair {0,1}: fused L1 (agg+bias+leaky+@W1, no h1 materialization)
        agg1_fused_kernel<<<2 * AGG_BLKS, 256, 0, stream>>>(
            rowptr4, colw, support0, b0, W1, s1a, s1b, 0);
        aggregate_kernel<false><<<2 * AGG_BLKS, 256, 0, stream>>>(
            rowptr4, colw, s1, b1, out, 0, 0);

        // pair {2,3}: reuse s1 regions (dead after previous L2 aggregate)
        agg1_fused_kernel<<<2 * AGG_BLKS, 256, 0, stream>>>(
            rowptr4, colw, support0, b0, W1, s1a, s1b, 2);
        aggregate_kernel<false><<<2 * AGG_BLKS, 256, 0, stream>>>(
            rowptr4, colw, s1, b1, out, 2, 0);
    } else {
        // fallback: per-graph serial (colw 3.2 MB reused, support1 in P32)
        unsigned* colwS = (unsigned*)(ws + 14429696);
        __half* support1 = (__half*)P32;
        for (int b = 0; b < BATCH; ++b) {
            placement_kernel<<<K_CHUNK * 2, 512, 0, stream>>>(
                ei, ew, flag, P16, rowptr4, colwS, b, b * N_EDGES);
            HPtr4 s0 = {{support0, support0, support0, support0}};
            aggregate_kernel<true><<<AGG_BLKS, 256, 0, stream>>>(
                rowptr4, colwS, s0, b0, out, b, 1);
            const __half* h1 = (const __half*)(out + b * ND);
            gemm_kernel<true, __half><<<GBLK, 256, 0, stream>>>(h1, W1, support1);
            HPtr4 s1 = {{support1, support1, support1, support1}};
            aggregate_kernel<false><<<AGG_BLKS, 256, 0, stream>>>(
                rowptr4, colwS, s1, b1, out, b, 1);
        }
    }
}

// Round 18
// 388.267 us; speedup vs baseline: 1.3390x; 1.3390x over previous
//
#include <hip/hip_runtime.h>
#include <hip/hip_fp16.h>
#include <type_traits>

#define N_NODES 50000
#define NROW    50176                    // padded rows per graph (multiple of 1024)
#define N_EDGES 800000
#define BATCH   4
#define DIM     64
#define NEG_SLOPE 0.2f
#define K_CHUNK 32
#define CHUNK_E (N_EDGES / K_CHUNK)      // 25000 exactly (u16-safe)
#define NTOT2   (BATCH * NROW)           // 200704 = 196*1024 exactly
#define SCAN_BLOCKS (NTOT2 / 1024)       // 196
#define HALF_ROWS 25088                  // NROW/2
#define HALF_WORDS 12544                 // HALF_ROWS/2 packed u16 words
#define GBLK    ((N_NODES + 63) / 64)    // 782 gemm blocks per graph
#define AGG_BLKS (NROW / 4)              // 12544

struct HPtr4 { const __half* p[4]; };
struct WPtr4 { __half* p[4]; };

// ---------------------------------------------------------------------------
// Index dtype detector (int64 vs int32).
// ---------------------------------------------------------------------------
__global__ void detect_idx_kernel(const unsigned* __restrict__ ei, int* flag) {
    __shared__ int any;
    if (threadIdx.x == 0) any = 0;
    __syncthreads();
    unsigned v = ei[threadIdx.x * 2 + 1];
    if (v != 0) atomicOr(&any, 1);
    __syncthreads();
    if (threadIdx.x == 0) *flag = (any ? 0 : 1);
}

__device__ __forceinline__ int load_idx(const void* p, long long i, int is64) {
    if (is64) return (int)(((const long long*)p)[i]);
    return ((const int*)p)[i];
}

// ---------------------------------------------------------------------------
// Histogram stage 1: private LDS histogram per (graph, chunk, row-half).
// 256 blocks (one per CU). u16 counters packed in u32.
// ---------------------------------------------------------------------------
__global__ __launch_bounds__(256)
void hist_partial_kernel(const void* __restrict__ ei, const int* __restrict__ flag,
                         unsigned* __restrict__ P32) {
    __shared__ unsigned lds[HALF_WORDS];          // 50 KB
    int t = threadIdx.x;
    int b = blockIdx.x >> 6;                      // 64 blocks per graph
    int k = (blockIdx.x >> 1) & (K_CHUNK - 1);
    int h = blockIdx.x & 1;
    for (int i = t; i < HALF_WORDS; i += 256) lds[i] = 0;
    __syncthreads();
    const int is64 = *flag;
    const int rowLo = h * HALF_ROWS;
    const long long base = (long long)b * 2LL * N_EDGES + (long long)k * CHUNK_E;
    for (int i = t; i < CHUNK_E; i += 256) {
        int row = load_idx(ei, base + i, is64);
        unsigned r = (unsigned)(row - rowLo);
        if (r < HALF_ROWS)
            atomicAdd(&lds[r >> 1], 1u << ((r & 1) * 16));
    }
    __syncthreads();
    unsigned* dst = P32 + (long long)(b * K_CHUNK + k) * (NROW / 2) + h * HALF_WORDS;
    for (int i = t; i < HALF_WORDS; i += 256) dst[i] = lds[i];
}

// ---------------------------------------------------------------------------
// Stage 2: per (b,row): deg = sum_k counts; P16 -> exclusive chunk prefix.
// ---------------------------------------------------------------------------
__global__ __launch_bounds__(256)
void merge_prefix_kernel(unsigned short* __restrict__ P16, int* __restrict__ deg4) {
    int gid = blockIdx.x * 256 + threadIdx.x;
    if (gid >= NTOT2) return;
    int b = gid / NROW;
    int row = gid - b * NROW;
    unsigned short* p = P16 + (long long)(b * K_CHUNK) * NROW + row;
    int run = 0;
#pragma unroll
    for (int k = 0; k < K_CHUNK; ++k) {
        int c = p[(long long)k * NROW];
        p[(long long)k * NROW] = (unsigned short)run;
        run += c;
    }
    deg4[gid] = run;
}

// ---------------------------------------------------------------------------
// Hierarchical exclusive scan over deg4[NTOT2] -> rowptr4.
// ---------------------------------------------------------------------------
__global__ __launch_bounds__(256)
void scan_partial_kernel(const int* __restrict__ deg, int* __restrict__ bsum) {
    __shared__ int sdata[256];
    int t = threadIdx.x;
    int base = blockIdx.x * 1024;
    int s = 0;
#pragma unroll
    for (int i = 0; i < 4; ++i) s += deg[base + i * 256 + t];
    sdata[t] = s;
    __syncthreads();
    for (int off = 128; off > 0; off >>= 1) {
        if (t < off) sdata[t] += sdata[t + off];
        __syncthreads();
    }
    if (t == 0) bsum[blockIdx.x] = sdata[0];
}

__global__ __launch_bounds__(256)
void scan_bsum_kernel(int* __restrict__ bsum, int* __restrict__ rowptr) {
    __shared__ int sdata[256];
    int t = threadIdx.x;
    int v = (t < SCAN_BLOCKS) ? bsum[t] : 0;
    sdata[t] = v;
    __syncthreads();
    for (int off = 1; off < 256; off <<= 1) {
        int x = (t >= off) ? sdata[t - off] : 0;
        __syncthreads();
        sdata[t] += x;
        __syncthreads();
    }
    if (t < SCAN_BLOCKS) bsum[t] = sdata[t] - v;
    if (t == 255) rowptr[NTOT2] = sdata[255];
}

__global__ __launch_bounds__(256)
void scan_apply_kernel(const int* __restrict__ deg, const int* __restrict__ bsum,
                       int* __restrict__ rowptr) {
    __shared__ int sdata[256];
    int t = threadIdx.x;
    int base = blockIdx.x * 1024 + t * 4;
    int4 q = *(const int4*)(deg + base);          // NTOT2 exact multiple of 1024
    int s = q.x + q.y + q.z + q.w;
    sdata[t] = s;
    __syncthreads();
    for (int off = 1; off < 256; off <<= 1) {
        int x = (t >= off) ? sdata[t - off] : 0;
        __syncthreads();
        sdata[t] += x;
        __syncthreads();
    }
    int run = bsum[blockIdx.x] + sdata[t] - s;
    rowptr[base + 0] = run; run += q.x;
    rowptr[base + 1] = run; run += q.y;
    rowptr[base + 2] = run; run += q.z;
    rowptr[base + 3] = run;
}

// ---------------------------------------------------------------------------
// Deterministic placement (R11 proven form, 256 blocks): NO global atomics.
// colw entry u32 = col(u16) | fp16 weight << 16
// ---------------------------------------------------------------------------
__global__ __launch_bounds__(512)
void placement_kernel(const void* __restrict__ ei, const float* __restrict__ ew,
                      const int* __restrict__ flag,
                      const unsigned short* __restrict__ P16,
                      const int* __restrict__ rowptr4,
                      unsigned* __restrict__ colw, int bStart, int sub) {
    __shared__ unsigned lds[HALF_WORDS];          // 50 KB packed u16 cursors
    const int is64 = *flag;
    const int nc = gridDim.x >> 5;                // classes = nGraphs*2 (32 chunks)
    int c = blockIdx.x % nc;
    int k = blockIdx.x / nc;                      // chunk 0..31
    int b = bStart + (c >> 1);
    int h = c & 1;
    const int rowLo = h * HALF_ROWS;
    const unsigned* psrc =
        (const unsigned*)(P16 + (long long)(b * K_CHUNK + k) * NROW + rowLo);
    for (int i = threadIdx.x; i < HALF_WORDS; i += 512) lds[i] = psrc[i];
    __syncthreads();
    const long long ebase = (long long)b * 2LL * N_EDGES + (long long)k * CHUNK_E;
    const float* ewb = ew + (long long)b * N_EDGES + (long long)k * CHUNK_E;
    const int* rp = rowptr4 + b * NROW;
    for (int i = threadIdx.x; i < CHUNK_E; i += 512) {
        int row = load_idx(ei, ebase + i, is64);
        unsigned r = (unsigned)(row - rowLo);
        if (r < HALF_ROWS) {
            int col = load_idx(ei, ebase + N_EDGES + i, is64);
            __half hw = __float2half_rn(ewb[i]);
            unsigned short wb = *(unsigned short*)&hw;
            unsigned old = atomicAdd(&lds[r >> 1], 1u << ((r & 1) * 16));
            int my = (int)((old >> ((r & 1) * 16)) & 0xffffu);
            int pos = rp[row] + my - sub;
            colw[pos] = (unsigned)col | ((unsigned)wb << 16);
        }
    }
}

// ---------------------------------------------------------------------------
// S = act(X) @ W -> fp16 [N][64]. TIN = float (bx) or __half (fp16 h1).
// ---------------------------------------------------------------------------
template <bool LEAKY, typename TIN>
__device__ __forceinline__
void gemm_body(const TIN* __restrict__ X, const float* __restrict__ Wl,
               __half* __restrict__ S, int blk, int t) {
    int dq = t & 15;
    int rl = t >> 4;
    int rowBase = blk * 64;
    for (int r = rl; r < 64; r += 16) {
        int row = rowBase + r;
        if (row >= N_NODES) break;
        const TIN* xr = X + (long long)row * DIM;
        float4 acc = {0.f, 0.f, 0.f, 0.f};
        if constexpr (std::is_same<TIN, float>::value) {
#pragma unroll
            for (int k = 0; k < 64; k += 4) {
                float4 xv = *(const float4*)(xr + k);
                if (LEAKY) {
                    xv.x = xv.x > 0.f ? xv.x : NEG_SLOPE * xv.x;
                    xv.y = xv.y > 0.f ? xv.y : NEG_SLOPE * xv.y;
                    xv.z = xv.z > 0.f ? xv.z : NEG_SLOPE * xv.z;
                    xv.w = xv.w > 0.f ? xv.w : NEG_SLOPE * xv.w;
                }
#pragma unroll
                for (int kk = 0; kk < 4; ++kk) {
                    float xs = kk == 0 ? xv.x : kk == 1 ? xv.y : kk == 2 ? xv.z : xv.w;
                    float4 wv = *(const float4*)(&Wl[(k + kk) * 64 + dq * 4]);
                    acc.x += xs * wv.x;
                    acc.y += xs * wv.y;
                    acc.z += xs * wv.z;
                    acc.w += xs * wv.w;
                }
            }
        } else {
#pragma unroll
            for (int k = 0; k < 64; k += 8) {
                float4 raw = *(const float4*)((const char*)xr + k * 2);  // 8 halfs
                const __half2* hp = (const __half2*)&raw;
                float xs[8];
#pragma unroll
                for (int j = 0; j < 4; ++j) {
                    float2 f = __half22float2(hp[j]);
                    xs[2 * j]     = f.x;
                    xs[2 * j + 1] = f.y;
                }
                if (LEAKY) {
#pragma unroll
                    for (int j = 0; j < 8; ++j)
                        xs[j] = xs[j] > 0.f ? xs[j] : NEG_SLOPE * xs[j];
                }
#pragma unroll
                for (int j = 0; j < 8; ++j) {
                    float4 wv = *(const float4*)(&Wl[(k + j) * 64 + dq * 4]);
                    acc.x += xs[j] * wv.x;
                    acc.y += xs[j] * wv.y;
                    acc.z += xs[j] * wv.z;
                    acc.w += xs[j] * wv.w;
                }
            }
        }
        __half2* o = (__half2*)(S + (long long)row * DIM + dq * 4);
        o[0] = __floats2half2_rn(acc.x, acc.y);
        o[1] = __floats2half2_rn(acc.z, acc.w);
    }
}

template <bool LEAKY, typename TIN>
__global__ __launch_bounds__(256)
void gemm_kernel(const TIN* __restrict__ X, const float* __restrict__ W,
                 __half* __restrict__ S) {
    __shared__ float Wl[64 * 64];
    int t = threadIdx.x;
    for (int i = t; i < 64 * 64; i += 256) Wl[i] = W[i];
    __syncthreads();
    gemm_body<LEAKY, TIN>(X, Wl, S, blockIdx.x, t);
}

// Batched layer-2 GEMM: one dispatch for all graphs.
__global__ __launch_bounds__(256)
void gemm2_kernel(const float* __restrict__ outBase, const float* __restrict__ W,
                  WPtr4 dsts) {
    __shared__ float Wl[64 * 64];
    int t = threadIdx.x;
    for (int i = t; i < 64 * 64; i += 256) Wl[i] = W[i];
    __syncthreads();
    int b   = blockIdx.x / GBLK;
    int blk = blockIdx.x % GBLK;
    const __half* X = (const __half*)(outBase + (long long)b * N_NODES * DIM);
    gemm_body<true, __half>(X, Wl, dsts.p[b], blk, t);
}

// ---------------------------------------------------------------------------
// Pull aggregation (R13 proven form), predicated window loop.
// HOUT=true: fp16 h1 into out slice; HOUT=false: final f32.
// ---------------------------------------------------------------------------
template <bool HOUT>
__global__ __launch_bounds__(256)
void aggregate_kernel(const int* __restrict__ rowptr4, const unsigned* __restrict__ colw,
                      HPtr4 srcs, const float* __restrict__ bias,
                      void* __restrict__ dstBase, int bStart, int colwLocal) {
    int bi = blockIdx.x / AGG_BLKS;
    int node = (blockIdx.x % AGG_BLKS) * 4 + (threadIdx.x >> 6);
    int tl = threadIdx.x & 63;
    int lane = tl & 31;
    int slot = tl >> 5;
    int b = bStart + bi;
    if (node >= N_NODES) return;
    const __half* __restrict__ src = srcs.p[b];
    const int* rp = rowptr4 + b * NROW;
    int sub = colwLocal ? b * N_EDGES : 0;
    int s = rp[node] - sub;
    int e = rp[node + 1] - sub;
    float2 acc = {0.f, 0.f};
    for (int k0 = s + slot; k0 < e; k0 += 16) {
        unsigned c[8];
        float2 v[8];
        bool m[8];
#pragma unroll
        for (int j = 0; j < 8; ++j) {
            int ki = k0 + 2 * j;
            m[j] = ki < e;
            c[j] = m[j] ? colw[ki] : 0u;
        }
#pragma unroll
        for (int j = 0; j < 8; ++j) {
            if (m[j]) {
                __half2 h = *(const __half2*)(src + (long long)(c[j] & 0xffffu) * DIM
                                              + 2 * lane);
                v[j] = __half22float2(h);
            } else {
                v[j] = make_float2(0.f, 0.f);
            }
        }
#pragma unroll
        for (int j = 0; j < 8; ++j) {
            unsigned short wb = (unsigned short)(c[j] >> 16);
            float w = __half2float(*(__half*)&wb);
            acc.x += w * v[j].x;
            acc.y += w * v[j].y;
        }
    }
    acc.x += __shfl_xor(acc.x, 32, 64);
    acc.y += __shfl_xor(acc.y, 32, 64);
    if (slot == 0) {
        float2 bb = *(const float2*)(bias + 2 * lane);
        float ox = acc.x + bb.x;
        float oy = acc.y + bb.y;
        char* gp = (char*)dstBase + (long long)b * ((long long)N_NODES * DIM * 4);
        if constexpr (HOUT) {
            __half2* hp = (__half2*)gp + (long long)node * (DIM / 2) + lane;
            *hp = __floats2half2_rn(ox, oy);
        } else {
            float2* fp = (float2*)gp + (long long)node * (DIM / 2) + lane;
            *fp = make_float2(ox, oy);
        }
    }
}

extern "C" void kernel_launch(void* const* d_in, const int* in_sizes, int n_in,
                              void* d_out, int out_size, void* d_ws, size_t ws_size,
                              hipStream_t stream) {
    const float* bx = (const float*)d_in[0];
    const void*  ei = d_in[1];
    const float* ew = (const float*)d_in[2];
    const float* W0 = (const float*)d_in[3];
    const float* b0 = (const float*)d_in[4];
    const float* W1 = (const float*)d_in[5];
    const float* b1 = (const float*)d_in[6];
    float* out = (float*)d_out;

    // ---- workspace layout (big path = 40,052,224 B) ----
    // [0,256) flag | [256,1280) bsum | [1280,804096) deg4
    // [804096,1607168) rowptr4
    // [1607168,14452224)  P32/P16: 4*32 chunk hists (12.845 MB)
    // [14452224,20852224) support0 fp16 (6.4 MB)
    // [20852224,33652224) colw packed (12.8 MB)
    // [33652224,40052224) tail s1 region (6.4 MB)
    char* ws = (char*)d_ws;
    int*      flag     = (int*)ws;
    int*      bsum     = (int*)(ws + 256);
    int*      deg4     = (int*)(ws + 1280);
    int*      rowptr4  = (int*)(ws + 804096);
    unsigned* P32      = (unsigned*)(ws + 1607168);
    unsigned short* P16 = (unsigned short*)P32;
    __half*   support0 = (__half*)(ws + 14452224);
    unsigned* colw     = (unsigned*)(ws + 20852224);
    const size_t NEED_BIG = 40052224ull;
    const bool big = ws_size >= NEED_BIG;
    const long long ND = (long long)N_NODES * DIM;

    detect_idx_kernel<<<1, 64, 0, stream>>>((const unsigned*)ei, flag);

    // ---- batched atomic-free CSR skeleton (256-block stages) ----
    hist_partial_kernel<<<BATCH * K_CHUNK * 2, 256, 0, stream>>>(ei, flag, P32);
    merge_prefix_kernel<<<(NTOT2 + 255) / 256, 256, 0, stream>>>(P16, deg4);
    scan_partial_kernel<<<SCAN_BLOCKS, 256, 0, stream>>>(deg4, bsum);
    scan_bsum_kernel<<<1, 256, 0, stream>>>(bsum, rowptr4);
    scan_apply_kernel<<<SCAN_BLOCKS, 256, 0, stream>>>(deg4, bsum, rowptr4);

    // ---- layer-1 support (graph-independent, fp16) ----
    gemm_kernel<false, float><<<GBLK, 256, 0, stream>>>(bx, W0, support0);

    if (big) {
        placement_kernel<<<BATCH * K_CHUNK * 2, 512, 0, stream>>>(
            ei, ew, flag, P16, rowptr4, colw, 0, 0);

        // L1 aggregate (batched, fp16 h1 into out slices)
        HPtr4 s0 = {{support0, support0, support0, support0}};
        aggregate_kernel<true><<<BATCH * AGG_BLKS, 256, 0, stream>>>(
            rowptr4, colw, s0, b0, out, 0, 0);

        // support1 regions: dead P32 (12.85 MB -> two slots), dead support0, tail
        WPtr4 s1w = {{(__half*)(ws + 1607168), (__half*)(ws + 8007168),
                      (__half*)(ws + 14452224), (__half*)(ws + 33652224)}};
        gemm2_kernel<<<BATCH * GBLK, 256, 0, stream>>>(out, W1, s1w);

        HPtr4 s1 = {{s1w.p[0], s1w.p[1], s1w.p[2], s1w.p[3]}};
        aggregate_kernel<false><<<BATCH * AGG_BLKS, 256, 0, stream>>>(
            rowptr4, colw, s1, b1, out, 0, 0);
    } else {
        // fallback: per-graph serial (colw per-graph 3.2 MB, support1 in P32)
        __half* support1 = (__half*)P32;
        for (int b = 0; b < BATCH; ++b) {
            placement_kernel<<<K_CHUNK * 2, 512, 0, stream>>>(
                ei, ew, flag, P16, rowptr4, colw, b, b * N_EDGES);
            HPtr4 s0 = {{support0, support0, support0, support0}};
            aggregate_kernel<true><<<AGG_BLKS, 256, 0, stream>>>(
                rowptr4, colw, s0, b0, out, b, 1);
            const __half* h1 = (const __half*)(out + b * ND);
            gemm_kernel<true, __half><<<GBLK, 256, 0, stream>>>(h1, W1, support1);
            HPtr4 s1 = {{support1, support1, support1, support1}};
            aggregate_kernel<false><<<AGG_BLKS, 256, 0, stream>>>(
                rowptr4, colw, s1, b1, out, b, 1);
        }
    }
}

// Round 19
// 304.485 us; speedup vs baseline: 1.7075x; 1.2752x over previous
//
#include <hip/hip_runtime.h>
#include <hip/hip_fp16.h>
#include <type_traits>

#define N_NODES 50000
#define NROW    50176                    // padded rows per graph (multiple of 1024)
#define N_EDGES 800000
#define BATCH   4
#define DIM     64
#define NEG_SLOPE 0.2f
#define K_CHUNK 32
#define CHUNK_E (N_EDGES / K_CHUNK)      // 25000 exactly (u16-safe)
#define NTOT2   (BATCH * NROW)           // 200704 = 196*1024 exactly
#define SCAN_BLOCKS (NTOT2 / 1024)       // 196
#define HALF_ROWS 25088                  // NROW/2
#define HALF_WORDS 12544                 // HALF_ROWS/2 packed u16 words
#define GBLK    ((N_NODES + 63) / 64)    // 782 gemm blocks per graph
#define AGG_BLKS (NROW / 4)              // 12544

struct HPtr4 { const __half* p[4]; };
struct WPtr4 { __half* p[4]; };

// ---------------------------------------------------------------------------
// Index dtype detector (int64 vs int32).
// ---------------------------------------------------------------------------
__global__ void detect_idx_kernel(const unsigned* __restrict__ ei, int* flag) {
    __shared__ int any;
    if (threadIdx.x == 0) any = 0;
    __syncthreads();
    unsigned v = ei[threadIdx.x * 2 + 1];
    if (v != 0) atomicOr(&any, 1);
    __syncthreads();
    if (threadIdx.x == 0) *flag = (any ? 0 : 1);
}

__device__ __forceinline__ int load_idx(const void* p, long long i, int is64) {
    if (is64) return (int)(((const long long*)p)[i]);
    return ((const int*)p)[i];
}

// ---------------------------------------------------------------------------
// Histogram stage 1: private LDS histogram per (graph, chunk, row-half).
// 256 blocks. u16 counters packed in u32.
// ---------------------------------------------------------------------------
__global__ __launch_bounds__(256)
void hist_partial_kernel(const void* __restrict__ ei, const int* __restrict__ flag,
                         unsigned* __restrict__ P32) {
    __shared__ unsigned lds[HALF_WORDS];          // 50 KB
    int t = threadIdx.x;
    int b = blockIdx.x >> 6;                      // 64 blocks per graph
    int k = (blockIdx.x >> 1) & (K_CHUNK - 1);
    int h = blockIdx.x & 1;
    for (int i = t; i < HALF_WORDS; i += 256) lds[i] = 0;
    __syncthreads();
    const int is64 = *flag;
    const int rowLo = h * HALF_ROWS;
    const long long base = (long long)b * 2LL * N_EDGES + (long long)k * CHUNK_E;
    for (int i = t; i < CHUNK_E; i += 256) {
        int row = load_idx(ei, base + i, is64);
        unsigned r = (unsigned)(row - rowLo);
        if (r < HALF_ROWS)
            atomicAdd(&lds[r >> 1], 1u << ((r & 1) * 16));
    }
    __syncthreads();
    unsigned* dst = P32 + (long long)(b * K_CHUNK + k) * (NROW / 2) + h * HALF_WORDS;
    for (int i = t; i < HALF_WORDS; i += 256) dst[i] = lds[i];
}

// ---------------------------------------------------------------------------
// Stage 2: per (b,row): deg = sum_k counts; P16 -> exclusive chunk prefix.
// ---------------------------------------------------------------------------
__global__ __launch_bounds__(256)
void merge_prefix_kernel(unsigned short* __restrict__ P16, int* __restrict__ deg4) {
    int gid = blockIdx.x * 256 + threadIdx.x;
    if (gid >= NTOT2) return;
    int b = gid / NROW;
    int row = gid - b * NROW;
    unsigned short* p = P16 + (long long)(b * K_CHUNK) * NROW + row;
    int run = 0;
#pragma unroll
    for (int k = 0; k < K_CHUNK; ++k) {
        int c = p[(long long)k * NROW];
        p[(long long)k * NROW] = (unsigned short)run;
        run += c;
    }
    deg4[gid] = run;
}

// ---------------------------------------------------------------------------
// Hierarchical exclusive scan over deg4[NTOT2] -> rowptr4.
// ---------------------------------------------------------------------------
__global__ __launch_bounds__(256)
void scan_partial_kernel(const int* __restrict__ deg, int* __restrict__ bsum) {
    __shared__ int sdata[256];
    int t = threadIdx.x;
    int base = blockIdx.x * 1024;
    int s = 0;
#pragma unroll
    for (int i = 0; i < 4; ++i) s += deg[base + i * 256 + t];
    sdata[t] = s;
    __syncthreads();
    for (int off = 128; off > 0; off >>= 1) {
        if (t < off) sdata[t] += sdata[t + off];
        __syncthreads();
    }
    if (t == 0) bsum[blockIdx.x] = sdata[0];
}

__global__ __launch_bounds__(256)
void scan_bsum_kernel(int* __restrict__ bsum, int* __restrict__ rowptr) {
    __shared__ int sdata[256];
    int t = threadIdx.x;
    int v = (t < SCAN_BLOCKS) ? bsum[t] : 0;
    sdata[t] = v;
    __syncthreads();
    for (int off = 1; off < 256; off <<= 1) {
        int x = (t >= off) ? sdata[t - off] : 0;
        __syncthreads();
        sdata[t] += x;
        __syncthreads();
    }
    if (t < SCAN_BLOCKS) bsum[t] = sdata[t] - v;
    if (t == 255) rowptr[NTOT2] = sdata[255];
}

__global__ __launch_bounds__(256)
void scan_apply_kernel(const int* __restrict__ deg, const int* __restrict__ bsum,
                       int* __restrict__ rowptr) {
    __shared__ int sdata[256];
    int t = threadIdx.x;
    int base = blockIdx.x * 1024 + t * 4;
    int4 q = *(const int4*)(deg + base);          // NTOT2 exact multiple of 1024
    int s = q.x + q.y + q.z + q.w;
    sdata[t] = s;
    __syncthreads();
    for (int off = 1; off < 256; off <<= 1) {
        int x = (t >= off) ? sdata[t - off] : 0;
        __syncthreads();
        sdata[t] += x;
        __syncthreads();
    }
    int run = bsum[blockIdx.x] + sdata[t] - s;
    rowptr[base + 0] = run; run += q.x;
    rowptr[base + 1] = run; run += q.y;
    rowptr[base + 2] = run; run += q.z;
    rowptr[base + 3] = run;
}

// ---------------------------------------------------------------------------
// Deterministic placement (R11 form, 256 blocks): NO global atomics.
// colw entry u32 = col(u16) | fp16 weight << 16
// ---------------------------------------------------------------------------
__global__ __launch_bounds__(512)
void placement_kernel(const void* __restrict__ ei, const float* __restrict__ ew,
                      const int* __restrict__ flag,
                      const unsigned short* __restrict__ P16,
                      const int* __restrict__ rowptr4,
                      unsigned* __restrict__ colw, int bStart, int sub) {
    __shared__ unsigned lds[HALF_WORDS];          // 50 KB packed u16 cursors
    const int is64 = *flag;
    const int nc = gridDim.x >> 5;                // classes = nGraphs*2 (32 chunks)
    int c = blockIdx.x % nc;
    int k = blockIdx.x / nc;                      // chunk 0..31
    int b = bStart + (c >> 1);
    int h = c & 1;
    const int rowLo = h * HALF_ROWS;
    const unsigned* psrc =
        (const unsigned*)(P16 + (long long)(b * K_CHUNK + k) * NROW + rowLo);
    for (int i = threadIdx.x; i < HALF_WORDS; i += 512) lds[i] = psrc[i];
    __syncthreads();
    const long long ebase = (long long)b * 2LL * N_EDGES + (long long)k * CHUNK_E;
    const float* ewb = ew + (long long)b * N_EDGES + (long long)k * CHUNK_E;
    const int* rp = rowptr4 + b * NROW;
    for (int i = threadIdx.x; i < CHUNK_E; i += 512) {
        int row = load_idx(ei, ebase + i, is64);
        unsigned r = (unsigned)(row - rowLo);
        if (r < HALF_ROWS) {
            int col = load_idx(ei, ebase + N_EDGES + i, is64);
            __half hw = __float2half_rn(ewb[i]);
            unsigned short wb = *(unsigned short*)&hw;
            unsigned old = atomicAdd(&lds[r >> 1], 1u << ((r & 1) * 16));
            int my = (int)((old >> ((r & 1) * 16)) & 0xffffu);
            int pos = rp[row] + my - sub;
            colw[pos] = (unsigned)col | ((unsigned)wb << 16);
        }
    }
}

// ---------------------------------------------------------------------------
// S = act(X) @ W -> fp16 [N][64]. TIN = float (bx) or __half (fp16 h1).
// ---------------------------------------------------------------------------
template <bool LEAKY, typename TIN>
__device__ __forceinline__
void gemm_body(const TIN* __restrict__ X, const float* __restrict__ Wl,
               __half* __restrict__ S, int blk, int t) {
    int dq = t & 15;
    int rl = t >> 4;
    int rowBase = blk * 64;
    for (int r = rl; r < 64; r += 16) {
        int row = rowBase + r;
        if (row >= N_NODES) break;
        const TIN* xr = X + (long long)row * DIM;
        float4 acc = {0.f, 0.f, 0.f, 0.f};
        if constexpr (std::is_same<TIN, float>::value) {
#pragma unroll
            for (int k = 0; k < 64; k += 4) {
                float4 xv = *(const float4*)(xr + k);
                if (LEAKY) {
                    xv.x = xv.x > 0.f ? xv.x : NEG_SLOPE * xv.x;
                    xv.y = xv.y > 0.f ? xv.y : NEG_SLOPE * xv.y;
                    xv.z = xv.z > 0.f ? xv.z : NEG_SLOPE * xv.z;
                    xv.w = xv.w > 0.f ? xv.w : NEG_SLOPE * xv.w;
                }
#pragma unroll
                for (int kk = 0; kk < 4; ++kk) {
                    float xs = kk == 0 ? xv.x : kk == 1 ? xv.y : kk == 2 ? xv.z : xv.w;
                    float4 wv = *(const float4*)(&Wl[(k + kk) * 64 + dq * 4]);
                    acc.x += xs * wv.x;
                    acc.y += xs * wv.y;
                    acc.z += xs * wv.z;
                    acc.w += xs * wv.w;
                }
            }
        } else {
#pragma unroll
            for (int k = 0; k < 64; k += 8) {
                float4 raw = *(const float4*)((const char*)xr + k * 2);  // 8 halfs
                const __half2* hp = (const __half2*)&raw;
                float xs[8];
#pragma unroll
                for (int j = 0; j < 4; ++j) {
                    float2 f = __half22float2(hp[j]);
                    xs[2 * j]     = f.x;
                    xs[2 * j + 1] = f.y;
                }
                if (LEAKY) {
#pragma unroll
                    for (int j = 0; j < 8; ++j)
                        xs[j] = xs[j] > 0.f ? xs[j] : NEG_SLOPE * xs[j];
                }
#pragma unroll
                for (int j = 0; j < 8; ++j) {
                    float4 wv = *(const float4*)(&Wl[(k + j) * 64 + dq * 4]);
                    acc.x += xs[j] * wv.x;
                    acc.y += xs[j] * wv.y;
                    acc.z += xs[j] * wv.z;
                    acc.w += xs[j] * wv.w;
                }
            }
        }
        __half2* o = (__half2*)(S + (long long)row * DIM + dq * 4);
        o[0] = __floats2half2_rn(acc.x, acc.y);
        o[1] = __floats2half2_rn(acc.z, acc.w);
    }
}

template <bool LEAKY, typename TIN>
__global__ __launch_bounds__(256)
void gemm_kernel(const TIN* __restrict__ X, const float* __restrict__ W,
                 __half* __restrict__ S) {
    __shared__ float Wl[64 * 64];
    int t = threadIdx.x;
    for (int i = t; i < 64 * 64; i += 256) Wl[i] = W[i];
    __syncthreads();
    gemm_body<LEAKY, TIN>(X, Wl, S, blockIdx.x, t);
}

// Batched layer-2 GEMM: one dispatch for all graphs.
__global__ __launch_bounds__(256)
void gemm2_kernel(const float* __restrict__ outBase, const float* __restrict__ W,
                  WPtr4 dsts) {
    __shared__ float Wl[64 * 64];
    int t = threadIdx.x;
    for (int i = t; i < 64 * 64; i += 256) Wl[i] = W[i];
    __syncthreads();
    int b   = blockIdx.x / GBLK;
    int blk = blockIdx.x % GBLK;
    const __half* X = (const __half*)(outBase + (long long)b * N_NODES * DIM);
    gemm_body<true, __half>(X, Wl, dsts.p[b], blk, t);
}

// ---------------------------------------------------------------------------
// Pull aggregation, low-VALU form: fp16 packed accumulate (__hfma2 = 1 op
// replaces 3 cvt + 2 fma), 32-bit shift-based gather addressing
// (row<<7 + 4*lane byte offset). Same memory pattern as R13/R17.
// ---------------------------------------------------------------------------
template <bool HOUT>
__global__ __launch_bounds__(256)
void aggregate_kernel(const int* __restrict__ rowptr4, const unsigned* __restrict__ colw,
                      HPtr4 srcs, const float* __restrict__ bias,
                      void* __restrict__ dstBase, int bStart, int colwLocal) {
    int bi = blockIdx.x / AGG_BLKS;
    int node = (blockIdx.x % AGG_BLKS) * 4 + (threadIdx.x >> 6);
    int tl = threadIdx.x & 63;
    int lane = tl & 31;
    int slot = tl >> 5;
    int b = bStart + bi;
    if (node >= N_NODES) return;
    const char* __restrict__ src = (const char*)srcs.p[b];
    const int* rp = rowptr4 + b * NROW;
    int sub = colwLocal ? b * N_EDGES : 0;
    int s = rp[node] - sub;
    int e = rp[node + 1] - sub;
    const unsigned laneOff = 4u * (unsigned)lane;
    __half2 acc = __floats2half2_rn(0.f, 0.f);
    for (int k0 = s + slot; k0 < e; k0 += 16) {
        unsigned c[8];
        __half2 v[8];
        bool m[8];
#pragma unroll
        for (int j = 0; j < 8; ++j) {
            int ki = k0 + 2 * j;
            m[j] = ki < e;
            c[j] = m[j] ? colw[ki] : 0u;           // masked: c=0 -> w=0
        }
#pragma unroll
        for (int j = 0; j < 8; ++j) {
            if (m[j]) {
                unsigned off = ((c[j] & 0xffffu) << 7) + laneOff;   // row*128B
                v[j] = *(const __half2*)(src + off);
            } else {
                v[j] = __floats2half2_rn(0.f, 0.f);
            }
        }
#pragma unroll
        for (int j = 0; j < 8; ++j) {
            unsigned wpack = (c[j] >> 16) * 0x00010001u;  // splat fp16 weight
            acc = __hfma2(*(const __half2*)&wpack, v[j], acc);
        }
    }
    // slot combine in packed fp16
    int ai = *(const int*)&acc;
    int oi = __shfl_xor(ai, 32, 64);
    acc = __hadd2(acc, *(const __half2*)&oi);
    if (slot == 0) {
        float2 av = __half22float2(acc);
        float2 bb = *(const float2*)(bias + 2 * lane);
        float ox = av.x + bb.x;
        float oy = av.y + bb.y;
        char* gp = (char*)dstBase + (long long)b * ((long long)N_NODES * DIM * 4);
        if constexpr (HOUT) {
            __half2* hp = (__half2*)gp + (long long)node * (DIM / 2) + lane;
            *hp = __floats2half2_rn(ox, oy);
        } else {
            float2* fp = (float2*)gp + (long long)node * (DIM / 2) + lane;
            *fp = make_float2(ox, oy);
        }
    }
}

extern "C" void kernel_launch(void* const* d_in, const int* in_sizes, int n_in,
                              void* d_out, int out_size, void* d_ws, size_t ws_size,
                              hipStream_t stream) {
    const float* bx = (const float*)d_in[0];
    const void*  ei = d_in[1];
    const float* ew = (const float*)d_in[2];
    const float* W0 = (const float*)d_in[3];
    const float* b0 = (const float*)d_in[4];
    const float* W1 = (const float*)d_in[5];
    const float* b1 = (const float*)d_in[6];
    float* out = (float*)d_out;

    // ---- workspace layout (big path = 40,052,224 B, proven R17) ----
    char* ws = (char*)d_ws;
    int*      flag     = (int*)ws;
    int*      bsum     = (int*)(ws + 256);
    int*      deg4     = (int*)(ws + 1280);
    int*      rowptr4  = (int*)(ws + 804096);
    unsigned* P32      = (unsigned*)(ws + 1607168);
    unsigned short* P16 = (unsigned short*)P32;
    __half*   support0 = (__half*)(ws + 14452224);
    unsigned* colw     = (unsigned*)(ws + 20852224);
    const size_t NEED_BIG = 40052224ull;
    const bool big = ws_size >= NEED_BIG;
    const long long ND = (long long)N_NODES * DIM;

    detect_idx_kernel<<<1, 64, 0, stream>>>((const unsigned*)ei, flag);

    // ---- batched atomic-free CSR skeleton (256-block stages) ----
    hist_partial_kernel<<<BATCH * K_CHUNK * 2, 256, 0, stream>>>(ei, flag, P32);
    merge_prefix_kernel<<<(NTOT2 + 255) / 256, 256, 0, stream>>>(P16, deg4);
    scan_partial_kernel<<<SCAN_BLOCKS, 256, 0, stream>>>(deg4, bsum);
    scan_bsum_kernel<<<1, 256, 0, stream>>>(bsum, rowptr4);
    scan_apply_kernel<<<SCAN_BLOCKS, 256, 0, stream>>>(deg4, bsum, rowptr4);

    // ---- layer-1 support (graph-independent, fp16) ----
    gemm_kernel<false, float><<<GBLK, 256, 0, stream>>>(bx, W0, support0);

    if (big) {
        placement_kernel<<<BATCH * K_CHUNK * 2, 512, 0, stream>>>(
            ei, ew, flag, P16, rowptr4, colw, 0, 0);

        // L1 aggregate (batched, fp16 h1 into out slices)
        HPtr4 s0 = {{support0, support0, support0, support0}};
        aggregate_kernel<true><<<BATCH * AGG_BLKS, 256, 0, stream>>>(
            rowptr4, colw, s0, b0, out, 0, 0);

        // support1 regions: dead P32 (two slots), dead support0, tail
        WPtr4 s1w = {{(__half*)(ws + 1607168), (__half*)(ws + 8007168),
                      (__half*)(ws + 14452224), (__half*)(ws + 33652224)}};
        gemm2_kernel<<<BATCH * GBLK, 256, 0, stream>>>(out, W1, s1w);

        HPtr4 s1 = {{s1w.p[0], s1w.p[1], s1w.p[2], s1w.p[3]}};
        aggregate_kernel<false><<<BATCH * AGG_BLKS, 256, 0, stream>>>(
            rowptr4, colw, s1, b1, out, 0, 0);
    } else {
        // fallback: per-graph serial (colw per-graph 3.2 MB, support1 in P32)
        __half* support1 = (__half*)P32;
        for (int b = 0; b < BATCH; ++b) {
            placement_kernel<<<K_CHUNK * 2, 512, 0, stream>>>(
                ei, ew, flag, P16, rowptr4, colw, b, b * N_EDGES);
            HPtr4 s0 = {{support0, support0, support0, support0}};
            aggregate_kernel<true><<<AGG_BLKS, 256, 0, stream>>>(
                rowptr4, colw, s0, b0, out, b, 1);
            const __half* h1 = (const __half*)(out + b * ND);
            gemm_kernel<true, __half><<<GBLK, 256, 0, stream>>>(h1, W1, support1);
            HPtr4 s1 = {{support1, support1, support1, support1}};
            aggregate_kernel<false><<<AGG_BLKS, 256, 0, stream>>>(
                rowptr4, colw, s1, b1, out, b, 1);
        }
    }
}